// Round 8
// baseline (1165.070 us; speedup 1.0000x reference)
//
#include <hip/hip_runtime.h>

#define NU 200000
#define NR 50000
#define DD 64
#define NE 2000000
#define NQ 500000
#define NBR 196   // ceil(NR/256)
#define NBU 782   // ceil(NU/256)
#define LDW 68    // padded LDS row stride (68*4B=272B: 16B-aligned, bank-shift 4)

// ---- dst-windowed CSR build parameters ----
#define NBS 98              // dst windows per side
#define BKT_CAP 24576       // pair capacity per window (mean 20480, +28 sigma)
#define LW_U 11             // 2048 users per window
#define LW_R 9              // 512 restaurants per window
#define PB_E 4096           // edges per binpass block
#define NPBB 489            // ceil(NE / PB_E)

// ---- binned decoder parameters ----
#define QWIN 448            // Pu rows per decoder window
#define NQW 447             // ceil(NU / QWIN)
#define QCAP 1536           // queries per window (mean 1120, +12 sigma)
#define QB_E 4096
#define NQB 123             // ceil(NQ / QB_E)

// -------------------- binpass: bin (src,dst) pairs by dst window -----------
__global__ __launch_bounds__(256)
void binpass_kernel(const int* __restrict__ ru_src, const int* __restrict__ ru_dst,
                    const int* __restrict__ ur_src, const int* __restrict__ ur_dst,
                    int* __restrict__ bcur, int2* __restrict__ pairs) {
    __shared__ int2 stg[PB_E];
    __shared__ unsigned char gstg[PB_E];
    __shared__ int hist[256];
    __shared__ int sca[256], scb[256];
    __shared__ int gpos[128];
    int side = (blockIdx.x >= NPBB) ? 1 : 0;
    int blk = side ? (blockIdx.x - NPBB) : blockIdx.x;
    const int* src = side ? ur_src : ru_src;
    const int* dst = side ? ur_dst : ru_dst;
    int lw = side ? LW_R : LW_U;
    int* bc = bcur + side * NBS;
    int2* region = pairs + (size_t)side * NBS * BKT_CAP;
    int tid = threadIdx.x;
    hist[tid] = 0;
    __syncthreads();
    int base = blk * PB_E;
    int myg[16]; int myrank[16]; int2 myp[16];
#pragma unroll
    for (int i = 0; i < 16; i++) {
        int e = base + i * 256 + tid;
        if (e < NE) {
            int d = dst[e];
            int g = d >> lw;
            myg[i] = g;
            myp[i] = make_int2(src[e], d);
            myrank[i] = atomicAdd(&hist[g], 1);
        } else myg[i] = -1;
    }
    __syncthreads();
    int h = hist[tid];
    sca[tid] = h;
    __syncthreads();
    int* cur = sca; int* alt = scb;
    for (int off = 1; off < 256; off <<= 1) {
        int x = cur[tid];
        if (tid >= off) x += cur[tid - off];
        alt[tid] = x;
        __syncthreads();
        int* tmp = cur; cur = alt; alt = tmp;
    }
    alt[tid] = cur[tid] - h;          // exclusive base per bucket
    if (tid < NBS && h > 0) gpos[tid] = atomicAdd(&bc[tid], h);
    __syncthreads();
    int* basep = alt;
#pragma unroll
    for (int i = 0; i < 16; i++) {
        if (myg[i] >= 0) {
            int p = basep[myg[i]] + myrank[i];
            stg[p] = myp[i];
            gstg[p] = (unsigned char)myg[i];
        }
    }
    __syncthreads();
    int tot = cur[255];
    for (int i = tid; i < tot; i += 256) {
        int g = gstg[i];
        int o = g * BKT_CAP + gpos[g] + (i - basep[g]);
        region[o] = stg[i];
    }
}

// -------------------- bbase: scan 98 window totals per side ----------------
__global__ void bbase_kernel(const int* __restrict__ bcur, int* __restrict__ bbase,
                             int* __restrict__ rs_u, int* __restrict__ rs_r) {
    __shared__ int a[128], b[128];
    int sidx = blockIdx.x;
    const int* bc = bcur + sidx * NBS;
    int* bb = bbase + sidx * NBS;
    int tid = threadIdx.x;
    a[tid] = (tid < NBS) ? bc[tid] : 0;
    __syncthreads();
    int* cur = a; int* alt = b;
    for (int off = 1; off < 128; off <<= 1) {
        int t = cur[tid];
        if (tid >= off) t += cur[tid - off];
        alt[tid] = t;
        __syncthreads();
        int* tmp = cur; cur = alt; alt = tmp;
    }
    if (tid < NBS) bb[tid] = (tid == 0) ? 0 : cur[tid - 1];
    if (tid == 0) { if (sidx == 0) rs_u[NU] = NE; else rs_r[NR] = NE; }
}

// -------------------- fillpass: per-window count/scan/scatter in LDS -------
__global__ __launch_bounds__(256)
void fillpass_kernel(const int2* __restrict__ pairs, const int* __restrict__ bcur,
                     const int* __restrict__ bbase,
                     int* __restrict__ rs_u, int* __restrict__ rs_r,
                     int* __restrict__ csr_u, int* __restrict__ csr_r) {
    __shared__ int win[BKT_CAP];      // 96 KB CSR window image
    __shared__ int lcnt[2048];        // 8 KB
    __shared__ int lofs[2048];        // 8 KB
    __shared__ int tsc[256], tsc2[256];
    int side = (blockIdx.x >= NBS) ? 1 : 0;
    int bkt = side ? (blockIdx.x - NBS) : blockIdx.x;
    const int2* reg = pairs + ((size_t)side * NBS + bkt) * BKT_CAP;
    int* rs = side ? rs_r : rs_u;
    int* csr = side ? csr_r : csr_u;
    int W = side ? 512 : 2048;
    int lw = side ? LW_R : LW_U;
    int n = side ? NR : NU;
    int d0 = bkt << lw;
    int tot = bcur[side * NBS + bkt];
    int base = bbase[side * NBS + bkt];
    int tid = threadIdx.x;
    for (int i = tid; i < W; i += 256) lcnt[i] = 0;
    __syncthreads();
    // pass 1: local degree count
    for (int i = tid; i < tot; i += 256) {
        int2 p = reg[i];
        atomicAdd(&lcnt[p.y - d0], 1);
    }
    __syncthreads();
    // exclusive scan of W counters (thread-chunked + block scan)
    int per = W >> 8;                 // 8 (user) or 2 (rest)
    int b0 = tid * per;
    int run = 0;
    for (int i = 0; i < per; i++) { int v = lcnt[b0 + i]; lofs[b0 + i] = run; run += v; }
    tsc[tid] = run;
    __syncthreads();
    int* cur = tsc; int* alt = tsc2;
    for (int off = 1; off < 256; off <<= 1) {
        int x = cur[tid];
        if (tid >= off) x += cur[tid - off];
        alt[tid] = x;
        __syncthreads();
        int* tmp = cur; cur = alt; alt = tmp;
    }
    int texcl = cur[tid] - run;
    for (int i = 0; i < per; i++) lofs[b0 + i] += texcl;
    __syncthreads();
    // write rs window (coalesced)
    int wn = min(W, n - d0);
    for (int i = tid; i < wn; i += 256) rs[d0 + i] = base + lofs[i];
    __syncthreads();
    // pass 2: slot assignment via LDS cursor + LDS scatter
    for (int i = tid; i < tot; i += 256) {
        int2 p = reg[i];
        int slot = atomicAdd(&lofs[p.y - d0], 1);
        win[slot] = p.x;
    }
    __syncthreads();
    // stream out (coalesced)
    for (int i = tid; i < tot; i += 256) csr[base + i] = win[i];
}

// -------------------- fused gather mean: wave per dst row, 16x4 groups -----
// (R6 form: 2-deep float4 loads — measured best; 4-deep regressed.)
__global__ __launch_bounds__(256)
void gather2_kernel(const float* __restrict__ hu, const int* __restrict__ csr_r,
                    const int* __restrict__ rs_r, float* __restrict__ mean_r,
                    const float* __restrict__ hr, const int* __restrict__ csr_u,
                    const int* __restrict__ rs_u, float* __restrict__ mean_u) {
    int lane = threadIdx.x & 63;
    int wave = blockIdx.x * 4 + (threadIdx.x >> 6);
    const float* h; const int* csr; const int* rs; float* mean; int r;
    if (wave < NR) { h = hu; csr = csr_r; rs = rs_r; mean = mean_r; r = wave; }
    else if (wave < NR + NU) { h = hr; csr = csr_u; rs = rs_u; mean = mean_u; r = wave - NR; }
    else return;
    int s = rs[r], e = rs[r + 1];
    int g = lane >> 4;            // neighbor subgroup 0..3
    int fo = (lane & 15) << 2;    // feature offset 0,4,...,60
    float4 a0 = {0.f, 0.f, 0.f, 0.f};
    float4 a1 = {0.f, 0.f, 0.f, 0.f};
    for (int j = s; j < e; j += 64) {
        int rem = e - j;
        int nch = rem < 64 ? rem : 64;
        int li = lane < nch ? lane : nch - 1;
        int idx = csr[j + li];
        for (int kk = 0; kk < nch; kk += 8) {
            int j0 = kk + g;          // <= 59
            int j1 = kk + 4 + g;      // <= 63
            int i0 = __shfl(idx, j0);
            int i1 = __shfl(idx, j1);
            float4 x0 = *(const float4*)(h + (size_t)i0 * DD + fo);
            float4 x1 = *(const float4*)(h + (size_t)i1 * DD + fo);
            if (j0 < nch) { a0.x += x0.x; a0.y += x0.y; a0.z += x0.z; a0.w += x0.w; }
            if (j1 < nch) { a1.x += x1.x; a1.y += x1.y; a1.z += x1.z; a1.w += x1.w; }
        }
    }
    float4 acc;
    acc.x = a0.x + a1.x; acc.y = a0.y + a1.y;
    acc.z = a0.z + a1.z; acc.w = a0.w + a1.w;
    acc.x += __shfl_xor(acc.x, 16); acc.y += __shfl_xor(acc.y, 16);
    acc.z += __shfl_xor(acc.z, 16); acc.w += __shfl_xor(acc.w, 16);
    acc.x += __shfl_xor(acc.x, 32); acc.y += __shfl_xor(acc.y, 32);
    acc.z += __shfl_xor(acc.z, 32); acc.w += __shfl_xor(acc.w, 32);
    if (g == 0) {
        float inv = 1.0f / fmaxf((float)(e - s), 1.0f);
        acc.x *= inv; acc.y *= inv; acc.z *= inv; acc.w *= inv;
        *(float4*)(mean + (size_t)r * DD + fo) = acc;
    }
}

#define DOT4(A, B) ((A).x*(B).x + (A).y*(B).y + (A).z*(B).z + (A).w*(B).w)

// -------------------- fused SAGE linear: LDS-staged row tiles --------------
__global__ __launch_bounds__(256, 2)
void sage_fused_kernel(const float* __restrict__ mean_r, const float* __restrict__ hr,
                       const float* __restrict__ mean_u, const float* __restrict__ hu,
                       const float* __restrict__ Wl2, const float* __restrict__ Wr2,
                       const float* __restrict__ bl2,
                       float* __restrict__ out_r, float* __restrict__ out_u, int do_relu) {
    __shared__ __attribute__((aligned(16))) float Wls[DD * LDW];
    __shared__ __attribute__((aligned(16))) float Wrs[DD * LDW];
    __shared__ __attribute__((aligned(16))) float Ms[64 * LDW];
    __shared__ __attribute__((aligned(16))) float Xs[64 * LDW];
    __shared__ float bsh[DD];
    int side = (blockIdx.x < NBR) ? 0 : 1;
    const float* Wl = Wl2 + side * DD * DD;
    const float* Wr = Wr2 + side * DD * DD;
    const float* bl = bl2 + side * DD;
    const float* mean; const float* h; float* out; int n; int blk;
    if (side == 0) { mean = mean_r; h = hr; out = out_r; n = NR; blk = blockIdx.x; }
    else { mean = mean_u; h = hu; out = out_u; n = NU; blk = blockIdx.x - NBR; }
    int tid = threadIdx.x;
    for (int i = tid; i < DD * DD; i += 256) {
        int c = i >> 6, k = i & 63;
        Wls[c * LDW + k] = Wl[i];
        Wrs[c * LDW + k] = Wr[i];
    }
    if (tid < DD) bsh[tid] = bl[tid];
    int rgrp = tid & 15;
    int cgrp = tid >> 4;
    int cb = cgrp * 4;
    int r00 = blk * 256;
    for (int ch = 0; ch < 4; ch++) {
        int rc0 = r00 + ch * 64;
        __syncthreads();   // LDS reuse guard (also covers W load on ch=0)
        for (int i = tid; i < 1024; i += 256) {
            int row = i >> 4;
            int c4 = (i & 15) << 2;
            int gr = min(rc0 + row, n - 1);
            *(float4*)&Ms[row * LDW + c4] = *(const float4*)(mean + (size_t)gr * DD + c4);
            *(float4*)&Xs[row * LDW + c4] = *(const float4*)(h + (size_t)gr * DD + c4);
        }
        __syncthreads();
        float4 bias = {bsh[cb], bsh[cb + 1], bsh[cb + 2], bsh[cb + 3]};
        float4 acc0 = bias, acc1 = bias, acc2 = bias, acc3 = bias;
#pragma unroll 1
        for (int kc = 0; kc < DD; kc += 8) {
            float4 wl[4][2], wr[4][2];
#pragma unroll
            for (int c = 0; c < 4; c++) {
                wl[c][0] = *(const float4*)&Wls[(cb + c) * LDW + kc];
                wl[c][1] = *(const float4*)&Wls[(cb + c) * LDW + kc + 4];
                wr[c][0] = *(const float4*)&Wrs[(cb + c) * LDW + kc];
                wr[c][1] = *(const float4*)&Wrs[(cb + c) * LDW + kc + 4];
            }
#define SROW(J, ACC) { \
            int row_ = rgrp + 16 * (J); \
            float4 ma_ = *(const float4*)&Ms[row_ * LDW + kc]; \
            float4 mb_ = *(const float4*)&Ms[row_ * LDW + kc + 4]; \
            float4 xa_ = *(const float4*)&Xs[row_ * LDW + kc]; \
            float4 xb_ = *(const float4*)&Xs[row_ * LDW + kc + 4]; \
            ACC.x += DOT4(ma_,wl[0][0])+DOT4(mb_,wl[0][1])+DOT4(xa_,wr[0][0])+DOT4(xb_,wr[0][1]); \
            ACC.y += DOT4(ma_,wl[1][0])+DOT4(mb_,wl[1][1])+DOT4(xa_,wr[1][0])+DOT4(xb_,wr[1][1]); \
            ACC.z += DOT4(ma_,wl[2][0])+DOT4(mb_,wl[2][1])+DOT4(xa_,wr[2][0])+DOT4(xb_,wr[2][1]); \
            ACC.w += DOT4(ma_,wl[3][0])+DOT4(mb_,wl[3][1])+DOT4(xa_,wr[3][0])+DOT4(xb_,wr[3][1]); }
            SROW(0, acc0) SROW(1, acc1) SROW(2, acc2) SROW(3, acc3)
#undef SROW
        }
        if (do_relu) {
            acc0.x = fmaxf(acc0.x, 0.f); acc0.y = fmaxf(acc0.y, 0.f); acc0.z = fmaxf(acc0.z, 0.f); acc0.w = fmaxf(acc0.w, 0.f);
            acc1.x = fmaxf(acc1.x, 0.f); acc1.y = fmaxf(acc1.y, 0.f); acc1.z = fmaxf(acc1.z, 0.f); acc1.w = fmaxf(acc1.w, 0.f);
            acc2.x = fmaxf(acc2.x, 0.f); acc2.y = fmaxf(acc2.y, 0.f); acc2.z = fmaxf(acc2.z, 0.f); acc2.w = fmaxf(acc2.w, 0.f);
            acc3.x = fmaxf(acc3.x, 0.f); acc3.y = fmaxf(acc3.y, 0.f); acc3.z = fmaxf(acc3.z, 0.f); acc3.w = fmaxf(acc3.w, 0.f);
        }
        {
            int r0_ = rc0 + rgrp;
            if (r0_ < n)      *(float4*)(out + (size_t)r0_ * DD + cb) = acc0;
            if (r0_ + 16 < n) *(float4*)(out + (size_t)(r0_ + 16) * DD + cb) = acc1;
            if (r0_ + 32 < n) *(float4*)(out + (size_t)(r0_ + 32) * DD + cb) = acc2;
            if (r0_ + 48 < n) *(float4*)(out + (size_t)(r0_ + 48) * DD + cb) = acc3;
        }
    }
}

// -------------------- fused decoder layer-1 precompute (LDS-staged) --------
__global__ __launch_bounds__(256, 2)
void pre_fused_kernel(const float* __restrict__ hu, const float* __restrict__ hr,
                      const float* __restrict__ dW1, const float* __restrict__ db1,
                      float* __restrict__ P_u, float* __restrict__ P_r) {
    __shared__ __attribute__((aligned(16))) float Ws[DD * LDW];
    __shared__ __attribute__((aligned(16))) float Xs[64 * LDW];
    __shared__ float bsh[DD];
    int side = (blockIdx.x < NBU) ? 0 : 1;   // 0 = user (koff 0, bias), 1 = rest
    int koff = side ? DD : 0;
    const float* h; float* out; int n; int blk;
    if (side == 0) { h = hu; out = P_u; n = NU; blk = blockIdx.x; }
    else { h = hr; out = P_r; n = NR; blk = blockIdx.x - NBU; }
    int tid = threadIdx.x;
    for (int i = tid; i < DD * DD; i += 256) {
        int c = i >> 6, k = i & 63;
        Ws[c * LDW + k] = dW1[c * 2 * DD + koff + k];
    }
    if (tid < DD) bsh[tid] = side ? 0.f : db1[tid];
    int rgrp = tid & 15;
    int cgrp = tid >> 4;
    int cb = cgrp * 4;
    int r00 = blk * 256;
    for (int ch = 0; ch < 4; ch++) {
        int rc0 = r00 + ch * 64;
        __syncthreads();
        for (int i = tid; i < 1024; i += 256) {
            int row = i >> 4;
            int c4 = (i & 15) << 2;
            int gr = min(rc0 + row, n - 1);
            *(float4*)&Xs[row * LDW + c4] = *(const float4*)(h + (size_t)gr * DD + c4);
        }
        __syncthreads();
        float4 bias = {bsh[cb], bsh[cb + 1], bsh[cb + 2], bsh[cb + 3]};
        float4 acc0 = bias, acc1 = bias, acc2 = bias, acc3 = bias;
#pragma unroll 1
        for (int kc = 0; kc < DD; kc += 8) {
            float4 wv[4][2];
#pragma unroll
            for (int c = 0; c < 4; c++) {
                wv[c][0] = *(const float4*)&Ws[(cb + c) * LDW + kc];
                wv[c][1] = *(const float4*)&Ws[(cb + c) * LDW + kc + 4];
            }
#define PROW(J, ACC) { \
            int row_ = rgrp + 16 * (J); \
            float4 xa_ = *(const float4*)&Xs[row_ * LDW + kc]; \
            float4 xb_ = *(const float4*)&Xs[row_ * LDW + kc + 4]; \
            ACC.x += DOT4(xa_,wv[0][0])+DOT4(xb_,wv[0][1]); \
            ACC.y += DOT4(xa_,wv[1][0])+DOT4(xb_,wv[1][1]); \
            ACC.z += DOT4(xa_,wv[2][0])+DOT4(xb_,wv[2][1]); \
            ACC.w += DOT4(xa_,wv[3][0])+DOT4(xb_,wv[3][1]); }
            PROW(0, acc0) PROW(1, acc1) PROW(2, acc2) PROW(3, acc3)
#undef PROW
        }
        {
            int r0_ = rc0 + rgrp;
            if (r0_ < n)      *(float4*)(out + (size_t)r0_ * DD + cb) = acc0;
            if (r0_ + 16 < n) *(float4*)(out + (size_t)(r0_ + 16) * DD + cb) = acc1;
            if (r0_ + 32 < n) *(float4*)(out + (size_t)(r0_ + 32) * DD + cb) = acc2;
            if (r0_ + 48 < n) *(float4*)(out + (size_t)(r0_ + 48) * DD + cb) = acc3;
        }
    }
}

// -------------------- qbin: bin queries by 448-row Pu window ---------------
__global__ __launch_bounds__(256)
void qbin_kernel(const int* __restrict__ el_row, const int* __restrict__ el_col,
                 int* __restrict__ qcur, int2* __restrict__ qpairs) {
    __shared__ int2 stg[QB_E];            // 32KB
    __shared__ unsigned short gstg[QB_E]; // 8KB
    __shared__ int hist[512];
    __shared__ int sca[256], scb[256];
    __shared__ int gbase[512];
    __shared__ int gpos[512];
    int tid = threadIdx.x;
    hist[tid] = 0; hist[tid + 256] = 0;
    __syncthreads();
    int base = blockIdx.x * QB_E;
    int myg[16]; int myrank[16]; int2 myp[16];
#pragma unroll
    for (int i = 0; i < 16; i++) {
        int e = base + i * 256 + tid;
        if (e < NQ) {
            int row = el_row[e];
            int col = el_col[e];
            int g = row / QWIN;              // const-div -> magic mul
            int rowl = row - g * QWIN;
            myg[i] = g;
            myp[i] = make_int2((rowl << 16) | col, e);
            myrank[i] = atomicAdd(&hist[g], 1);
        } else myg[i] = -1;
    }
    __syncthreads();
    int b0 = tid * 2;
    int h0 = hist[b0], h1 = hist[b0 + 1];
    int run = h0 + h1;
    sca[tid] = run;
    __syncthreads();
    int* cur = sca; int* alt = scb;
    for (int off = 1; off < 256; off <<= 1) {
        int x = cur[tid];
        if (tid >= off) x += cur[tid - off];
        alt[tid] = x;
        __syncthreads();
        int* tmp = cur; cur = alt; alt = tmp;
    }
    int texcl = cur[tid] - run;
    gbase[b0] = texcl;
    gbase[b0 + 1] = texcl + h0;
    if (b0 < NQW && h0 > 0) gpos[b0] = atomicAdd(&qcur[b0], h0);
    if (b0 + 1 < NQW && h1 > 0) gpos[b0 + 1] = atomicAdd(&qcur[b0 + 1], h1);
    __syncthreads();
#pragma unroll
    for (int i = 0; i < 16; i++) {
        if (myg[i] >= 0) {
            int p = gbase[myg[i]] + myrank[i];
            stg[p] = myp[i];
            gstg[p] = (unsigned short)myg[i];
        }
    }
    __syncthreads();
    int tot = cur[255];
    for (int i = tid; i < tot; i += 256) {
        int g = gstg[i];
        int o = g * QCAP + gpos[g] + (i - gbase[g]);
        qpairs[o] = stg[i];
    }
}

// -------------------- qdec: binned decoder, wave-per-query -----------------
// Pu window slice staged in LDS (coalesced, one XCD owns it); W2 row c lives
// in lane c's registers; z broadcast via readlane (no LDS in inner loop).
__device__ __forceinline__ float rdlane(float v, int l) {
    return __int_as_float(__builtin_amdgcn_readlane(__float_as_int(v), l));
}

__global__ __launch_bounds__(512)
void qdec_kernel(const float* __restrict__ Pu, const float* __restrict__ Pr,
                 const int2* __restrict__ qpairs, const int* __restrict__ qcur,
                 const float* __restrict__ dW2, const float* __restrict__ db2,
                 const float* __restrict__ dW3, const float* __restrict__ db3,
                 float* __restrict__ out) {
    __shared__ __attribute__((aligned(16))) float Pus[QWIN * 68];  // 121856 B
    int w = blockIdx.x;
    int tid = threadIdx.x;
    int lane = tid & 63;
    int wv = tid >> 6;    // 8 waves
    int r0 = w * QWIN;
    for (int i = tid; i < QWIN * 16; i += 512) {
        int row = i >> 4, c4 = (i & 15) << 2;
        int gr = min(r0 + row, NU - 1);
        *(float4*)&Pus[row * 68 + c4] = *(const float4*)(Pu + (size_t)gr * DD + c4);
    }
    // lane c holds W2 row c (64 regs), b2[c], w3[c]
    float w2[64];
    {
        const float* wr = dW2 + (size_t)lane * DD;
#pragma unroll
        for (int k = 0; k < 64; k += 4) {
            float4 v = *(const float4*)(wr + k);
            w2[k] = v.x; w2[k + 1] = v.y; w2[k + 2] = v.z; w2[k + 3] = v.w;
        }
    }
    float b2l = db2[lane];
    float w3l = dW3[lane];
    float db3v = db3[0];
    __syncthreads();
    int tot = qcur[w];
    const int2* qp = qpairs + (size_t)w * QCAP;
    for (int qi = wv; qi < tot; qi += 16) {
        int2 pA = qp[qi];
        int hasB = (qi + 8) < tot;
        int2 pB = qp[hasB ? qi + 8 : qi];
        float prA = Pr[(size_t)(pA.x & 0xFFFF) * DD + lane];
        float prB = Pr[(size_t)(pB.x & 0xFFFF) * DD + lane];
        float zA = fmaxf(Pus[(pA.x >> 16) * 68 + lane] + prA, 0.f);
        float zB = fmaxf(Pus[(pB.x >> 16) * 68 + lane] + prB, 0.f);
        float sA = b2l, sB = b2l;
#pragma unroll
        for (int k = 0; k < 64; k++) {
            sA += rdlane(zA, k) * w2[k];
            sB += rdlane(zB, k) * w2[k];
        }
        float tA = fmaxf(sA, 0.f) * w3l;
        float tB = fmaxf(sB, 0.f) * w3l;
        tA += __shfl_xor(tA, 1);  tB += __shfl_xor(tB, 1);
        tA += __shfl_xor(tA, 2);  tB += __shfl_xor(tB, 2);
        tA += __shfl_xor(tA, 4);  tB += __shfl_xor(tB, 4);
        tA += __shfl_xor(tA, 8);  tB += __shfl_xor(tB, 8);
        tA += __shfl_xor(tA, 16); tB += __shfl_xor(tB, 16);
        tA += __shfl_xor(tA, 32); tB += __shfl_xor(tB, 32);
        if (lane == 0) {
            out[pA.y] = tA + db3v;
            if (hasB) out[pB.y] = tB + db3v;
        }
    }
}

extern "C" void kernel_launch(void* const* d_in, const int* in_sizes, int n_in,
                              void* d_out, int out_size, void* d_ws, size_t ws_size,
                              hipStream_t stream) {
    const float* x_user = (const float*)d_in[0];
    const float* x_rest = (const float*)d_in[1];
    const float* Wl     = (const float*)d_in[2];
    const float* Wr     = (const float*)d_in[3];
    const float* bl     = (const float*)d_in[4];
    const float* dW1    = (const float*)d_in[5];
    const float* db1    = (const float*)d_in[6];
    const float* dW2    = (const float*)d_in[7];
    const float* db2    = (const float*)d_in[8];
    const float* dW3    = (const float*)d_in[9];
    const float* db3    = (const float*)d_in[10];
    const int* ur_src   = (const int*)d_in[11];
    const int* ur_dst   = (const int*)d_in[12];
    const int* ru_src   = (const int*)d_in[13];
    const int* ru_dst   = (const int*)d_in[14];
    const int* el_row   = (const int*)d_in[15];
    const int* el_col   = (const int*)d_in[16];
    float* out = (float*)d_out;

    char* w = (char*)d_ws;
    size_t off = 0;
    auto alloc = [&](size_t bytes) -> void* {
        void* p = (void*)(w + off);
        off += (bytes + 255) & ~(size_t)255;
        return p;
    };
    float* hu0    = (float*)alloc((size_t)NU * DD * 4);
    float* hu1    = (float*)alloc((size_t)NU * DD * 4);
    float* hr0    = (float*)alloc((size_t)NR * DD * 4);
    float* hr1    = (float*)alloc((size_t)NR * DD * 4);
    float* mean_u = (float*)alloc((size_t)NU * DD * 4);
    float* mean_r = (float*)alloc((size_t)NR * DD * 4);
    int* csr_u  = (int*)alloc((size_t)NE * 4);
    int* csr_r  = (int*)alloc((size_t)NE * 4);
    int* rs_u   = (int*)alloc((size_t)(NU + 1) * 4);
    int* rs_r   = (int*)alloc((size_t)(NR + 1) * 4);
    int* bcur   = (int*)alloc((size_t)2 * NBS * 4);   // 784 -> pads to 1024
    int* bbase  = (int*)alloc((size_t)2 * NBS * 4);   // 784 -> pads to 1024
    int* qcur   = (int*)alloc((size_t)512 * 4);       // 2048

    // pair buffer carved from mean_u (free until gather writes it):
    // build: 2*98*24576*8B = 38.5MB <= 51.2MB. decoder: qpairs 447*1536*8B=5.5MB
    int2* pairs = (int2*)mean_u;
    int2* qpairs = (int2*)mean_u;

    // ---- CSR build: bin by dst window -> window-local count/scan/fill ----
    // one memset zeroes bcur (1024) + bbase (1024) + qcur (2048)
    hipMemsetAsync(bcur, 0, 4096, stream);
    binpass_kernel<<<2 * NPBB, 256, 0, stream>>>(ru_src, ru_dst, ur_src, ur_dst,
                                                 bcur, pairs);
    bbase_kernel<<<2, 128, 0, stream>>>(bcur, bbase, rs_u, rs_r);
    fillpass_kernel<<<2 * NBS, 256, 0, stream>>>(pairs, bcur, bbase,
                                                 rs_u, rs_r, csr_u, csr_r);

    // ---- 3 SAGE layers: 2 fused launches per layer ----
    const float* cu = x_user;
    const float* cr = x_rest;
    float* nu_[3] = {hu0, hu1, hu0};
    float* nr_[3] = {hr0, hr1, hr0};
    const int ggrid = (NR + NU + 3) / 4;   // 62500

    for (int l = 0; l < 3; l++) {
        const float* Wl2 = Wl + (size_t)l * 2 * DD * DD;
        const float* Wr2 = Wr + (size_t)l * 2 * DD * DD;
        const float* bl2 = bl + (size_t)l * 2 * DD;
        int relu = (l < 2) ? 1 : 0;
        gather2_kernel<<<ggrid, 256, 0, stream>>>(cu, csr_r, rs_r, mean_r,
                                                  cr, csr_u, rs_u, mean_u);
        sage_fused_kernel<<<NBR + NBU, 256, 0, stream>>>(mean_r, cr, mean_u, cu,
                                                         Wl2, Wr2, bl2,
                                                         nr_[l], nu_[l], relu);
        cu = nu_[l];
        cr = nr_[l];
    }
    // ---- decoder: precompute P, bin queries by Pu window, wave-per-query --
    float* P_u = hu1;
    float* P_r = hr1;
    pre_fused_kernel<<<NBU + NBR, 256, 0, stream>>>(cu, cr, dW1, db1, P_u, P_r);
    qbin_kernel<<<NQB, 256, 0, stream>>>(el_row, el_col, qcur, qpairs);
    qdec_kernel<<<NQW, 512, 0, stream>>>(P_u, P_r, qpairs, qcur,
                                         dW2, db2, dW3, db3, out);
}

// Round 9
// 1035.448 us; speedup vs baseline: 1.1252x; 1.1252x over previous
//
#include <hip/hip_runtime.h>

#define NU 200000
#define NR 50000
#define DD 64
#define NE 2000000
#define NQ 500000
#define NBR 196   // ceil(NR/256)
#define NBU 782   // ceil(NU/256)
#define LDW 68    // padded LDS row stride (68*4B=272B: 16B-aligned, bank-shift 4)

// ---- dst-windowed CSR build parameters ----
#define NBS 98              // dst windows per side
#define BKT_CAP 24576       // pair capacity per window (mean 20480, +28 sigma)
#define LW_U 11             // 2048 users per window
#define LW_R 9              // 512 restaurants per window
#define PB_E 4096           // edges per binpass block
#define NPBB 489            // ceil(NE / PB_E)

// ---- binned decoder parameters ----
#define QWIN 448            // Pu rows per decoder window
#define NQW 447             // ceil(NU / QWIN)
#define QCAP 1536           // queries per window (mean 1120, +12 sigma)
#define QB_E 4096
#define NQB 123             // ceil(NQ / QB_E)

// -------------------- binpass: bin (src,dst) pairs by dst window -----------
__global__ __launch_bounds__(256)
void binpass_kernel(const int* __restrict__ ru_src, const int* __restrict__ ru_dst,
                    const int* __restrict__ ur_src, const int* __restrict__ ur_dst,
                    int* __restrict__ bcur, int2* __restrict__ pairs) {
    __shared__ int2 stg[PB_E];
    __shared__ unsigned char gstg[PB_E];
    __shared__ int hist[256];
    __shared__ int sca[256], scb[256];
    __shared__ int gpos[128];
    int side = (blockIdx.x >= NPBB) ? 1 : 0;
    int blk = side ? (blockIdx.x - NPBB) : blockIdx.x;
    const int* src = side ? ur_src : ru_src;
    const int* dst = side ? ur_dst : ru_dst;
    int lw = side ? LW_R : LW_U;
    int* bc = bcur + side * NBS;
    int2* region = pairs + (size_t)side * NBS * BKT_CAP;
    int tid = threadIdx.x;
    hist[tid] = 0;
    __syncthreads();
    int base = blk * PB_E;
    int myg[16]; int myrank[16]; int2 myp[16];
#pragma unroll
    for (int i = 0; i < 16; i++) {
        int e = base + i * 256 + tid;
        if (e < NE) {
            int d = dst[e];
            int g = d >> lw;
            myg[i] = g;
            myp[i] = make_int2(src[e], d);
            myrank[i] = atomicAdd(&hist[g], 1);
        } else myg[i] = -1;
    }
    __syncthreads();
    int h = hist[tid];
    sca[tid] = h;
    __syncthreads();
    int* cur = sca; int* alt = scb;
    for (int off = 1; off < 256; off <<= 1) {
        int x = cur[tid];
        if (tid >= off) x += cur[tid - off];
        alt[tid] = x;
        __syncthreads();
        int* tmp = cur; cur = alt; alt = tmp;
    }
    alt[tid] = cur[tid] - h;          // exclusive base per bucket
    if (tid < NBS && h > 0) gpos[tid] = atomicAdd(&bc[tid], h);
    __syncthreads();
    int* basep = alt;
#pragma unroll
    for (int i = 0; i < 16; i++) {
        if (myg[i] >= 0) {
            int p = basep[myg[i]] + myrank[i];
            stg[p] = myp[i];
            gstg[p] = (unsigned char)myg[i];
        }
    }
    __syncthreads();
    int tot = cur[255];
    for (int i = tid; i < tot; i += 256) {
        int g = gstg[i];
        int o = g * BKT_CAP + gpos[g] + (i - basep[g]);
        region[o] = stg[i];
    }
}

// -------------------- bbase: scan 98 window totals per side ----------------
__global__ void bbase_kernel(const int* __restrict__ bcur, int* __restrict__ bbase,
                             int* __restrict__ rs_u, int* __restrict__ rs_r) {
    __shared__ int a[128], b[128];
    int sidx = blockIdx.x;
    const int* bc = bcur + sidx * NBS;
    int* bb = bbase + sidx * NBS;
    int tid = threadIdx.x;
    a[tid] = (tid < NBS) ? bc[tid] : 0;
    __syncthreads();
    int* cur = a; int* alt = b;
    for (int off = 1; off < 128; off <<= 1) {
        int t = cur[tid];
        if (tid >= off) t += cur[tid - off];
        alt[tid] = t;
        __syncthreads();
        int* tmp = cur; cur = alt; alt = tmp;
    }
    if (tid < NBS) bb[tid] = (tid == 0) ? 0 : cur[tid - 1];
    if (tid == 0) { if (sidx == 0) rs_u[NU] = NE; else rs_r[NR] = NE; }
}

// -------------------- fillpass: per-window count/scan/scatter in LDS -------
__global__ __launch_bounds__(256)
void fillpass_kernel(const int2* __restrict__ pairs, const int* __restrict__ bcur,
                     const int* __restrict__ bbase,
                     int* __restrict__ rs_u, int* __restrict__ rs_r,
                     int* __restrict__ csr_u, int* __restrict__ csr_r) {
    __shared__ int win[BKT_CAP];      // 96 KB CSR window image
    __shared__ int lcnt[2048];        // 8 KB
    __shared__ int lofs[2048];        // 8 KB
    __shared__ int tsc[256], tsc2[256];
    int side = (blockIdx.x >= NBS) ? 1 : 0;
    int bkt = side ? (blockIdx.x - NBS) : blockIdx.x;
    const int2* reg = pairs + ((size_t)side * NBS + bkt) * BKT_CAP;
    int* rs = side ? rs_r : rs_u;
    int* csr = side ? csr_r : csr_u;
    int W = side ? 512 : 2048;
    int lw = side ? LW_R : LW_U;
    int n = side ? NR : NU;
    int d0 = bkt << lw;
    int tot = bcur[side * NBS + bkt];
    int base = bbase[side * NBS + bkt];
    int tid = threadIdx.x;
    for (int i = tid; i < W; i += 256) lcnt[i] = 0;
    __syncthreads();
    // pass 1: local degree count
    for (int i = tid; i < tot; i += 256) {
        int2 p = reg[i];
        atomicAdd(&lcnt[p.y - d0], 1);
    }
    __syncthreads();
    // exclusive scan of W counters (thread-chunked + block scan)
    int per = W >> 8;                 // 8 (user) or 2 (rest)
    int b0 = tid * per;
    int run = 0;
    for (int i = 0; i < per; i++) { int v = lcnt[b0 + i]; lofs[b0 + i] = run; run += v; }
    tsc[tid] = run;
    __syncthreads();
    int* cur = tsc; int* alt = tsc2;
    for (int off = 1; off < 256; off <<= 1) {
        int x = cur[tid];
        if (tid >= off) x += cur[tid - off];
        alt[tid] = x;
        __syncthreads();
        int* tmp = cur; cur = alt; alt = tmp;
    }
    int texcl = cur[tid] - run;
    for (int i = 0; i < per; i++) lofs[b0 + i] += texcl;
    __syncthreads();
    // write rs window (coalesced)
    int wn = min(W, n - d0);
    for (int i = tid; i < wn; i += 256) rs[d0 + i] = base + lofs[i];
    __syncthreads();
    // pass 2: slot assignment via LDS cursor + LDS scatter
    for (int i = tid; i < tot; i += 256) {
        int2 p = reg[i];
        int slot = atomicAdd(&lofs[p.y - d0], 1);
        win[slot] = p.x;
    }
    __syncthreads();
    // stream out (coalesced)
    for (int i = tid; i < tot; i += 256) csr[base + i] = win[i];
}

// -------------------- fused gather mean: wave per dst row, 16x4 groups -----
// (R6 form: 2-deep float4 loads — measured best; 4-deep regressed.)
__global__ __launch_bounds__(256)
void gather2_kernel(const float* __restrict__ hu, const int* __restrict__ csr_r,
                    const int* __restrict__ rs_r, float* __restrict__ mean_r,
                    const float* __restrict__ hr, const int* __restrict__ csr_u,
                    const int* __restrict__ rs_u, float* __restrict__ mean_u) {
    int lane = threadIdx.x & 63;
    int wave = blockIdx.x * 4 + (threadIdx.x >> 6);
    const float* h; const int* csr; const int* rs; float* mean; int r;
    if (wave < NR) { h = hu; csr = csr_r; rs = rs_r; mean = mean_r; r = wave; }
    else if (wave < NR + NU) { h = hr; csr = csr_u; rs = rs_u; mean = mean_u; r = wave - NR; }
    else return;
    int s = rs[r], e = rs[r + 1];
    int g = lane >> 4;            // neighbor subgroup 0..3
    int fo = (lane & 15) << 2;    // feature offset 0,4,...,60
    float4 a0 = {0.f, 0.f, 0.f, 0.f};
    float4 a1 = {0.f, 0.f, 0.f, 0.f};
    for (int j = s; j < e; j += 64) {
        int rem = e - j;
        int nch = rem < 64 ? rem : 64;
        int li = lane < nch ? lane : nch - 1;
        int idx = csr[j + li];
        for (int kk = 0; kk < nch; kk += 8) {
            int j0 = kk + g;          // <= 59
            int j1 = kk + 4 + g;      // <= 63
            int i0 = __shfl(idx, j0);
            int i1 = __shfl(idx, j1);
            float4 x0 = *(const float4*)(h + (size_t)i0 * DD + fo);
            float4 x1 = *(const float4*)(h + (size_t)i1 * DD + fo);
            if (j0 < nch) { a0.x += x0.x; a0.y += x0.y; a0.z += x0.z; a0.w += x0.w; }
            if (j1 < nch) { a1.x += x1.x; a1.y += x1.y; a1.z += x1.z; a1.w += x1.w; }
        }
    }
    float4 acc;
    acc.x = a0.x + a1.x; acc.y = a0.y + a1.y;
    acc.z = a0.z + a1.z; acc.w = a0.w + a1.w;
    acc.x += __shfl_xor(acc.x, 16); acc.y += __shfl_xor(acc.y, 16);
    acc.z += __shfl_xor(acc.z, 16); acc.w += __shfl_xor(acc.w, 16);
    acc.x += __shfl_xor(acc.x, 32); acc.y += __shfl_xor(acc.y, 32);
    acc.z += __shfl_xor(acc.z, 32); acc.w += __shfl_xor(acc.w, 32);
    if (g == 0) {
        float inv = 1.0f / fmaxf((float)(e - s), 1.0f);
        acc.x *= inv; acc.y *= inv; acc.z *= inv; acc.w *= inv;
        *(float4*)(mean + (size_t)r * DD + fo) = acc;
    }
}

#define DOT4(A, B) ((A).x*(B).x + (A).y*(B).y + (A).z*(B).z + (A).w*(B).w)

// -------------------- fused SAGE linear: LDS-staged row tiles --------------
__global__ __launch_bounds__(256, 2)
void sage_fused_kernel(const float* __restrict__ mean_r, const float* __restrict__ hr,
                       const float* __restrict__ mean_u, const float* __restrict__ hu,
                       const float* __restrict__ Wl2, const float* __restrict__ Wr2,
                       const float* __restrict__ bl2,
                       float* __restrict__ out_r, float* __restrict__ out_u, int do_relu) {
    __shared__ __attribute__((aligned(16))) float Wls[DD * LDW];
    __shared__ __attribute__((aligned(16))) float Wrs[DD * LDW];
    __shared__ __attribute__((aligned(16))) float Ms[64 * LDW];
    __shared__ __attribute__((aligned(16))) float Xs[64 * LDW];
    __shared__ float bsh[DD];
    int side = (blockIdx.x < NBR) ? 0 : 1;
    const float* Wl = Wl2 + side * DD * DD;
    const float* Wr = Wr2 + side * DD * DD;
    const float* bl = bl2 + side * DD;
    const float* mean; const float* h; float* out; int n; int blk;
    if (side == 0) { mean = mean_r; h = hr; out = out_r; n = NR; blk = blockIdx.x; }
    else { mean = mean_u; h = hu; out = out_u; n = NU; blk = blockIdx.x - NBR; }
    int tid = threadIdx.x;
    for (int i = tid; i < DD * DD; i += 256) {
        int c = i >> 6, k = i & 63;
        Wls[c * LDW + k] = Wl[i];
        Wrs[c * LDW + k] = Wr[i];
    }
    if (tid < DD) bsh[tid] = bl[tid];
    int rgrp = tid & 15;
    int cgrp = tid >> 4;
    int cb = cgrp * 4;
    int r00 = blk * 256;
    for (int ch = 0; ch < 4; ch++) {
        int rc0 = r00 + ch * 64;
        __syncthreads();   // LDS reuse guard (also covers W load on ch=0)
        for (int i = tid; i < 1024; i += 256) {
            int row = i >> 4;
            int c4 = (i & 15) << 2;
            int gr = min(rc0 + row, n - 1);
            *(float4*)&Ms[row * LDW + c4] = *(const float4*)(mean + (size_t)gr * DD + c4);
            *(float4*)&Xs[row * LDW + c4] = *(const float4*)(h + (size_t)gr * DD + c4);
        }
        __syncthreads();
        float4 bias = {bsh[cb], bsh[cb + 1], bsh[cb + 2], bsh[cb + 3]};
        float4 acc0 = bias, acc1 = bias, acc2 = bias, acc3 = bias;
#pragma unroll 1
        for (int kc = 0; kc < DD; kc += 8) {
            float4 wl[4][2], wr[4][2];
#pragma unroll
            for (int c = 0; c < 4; c++) {
                wl[c][0] = *(const float4*)&Wls[(cb + c) * LDW + kc];
                wl[c][1] = *(const float4*)&Wls[(cb + c) * LDW + kc + 4];
                wr[c][0] = *(const float4*)&Wrs[(cb + c) * LDW + kc];
                wr[c][1] = *(const float4*)&Wrs[(cb + c) * LDW + kc + 4];
            }
#define SROW(J, ACC) { \
            int row_ = rgrp + 16 * (J); \
            float4 ma_ = *(const float4*)&Ms[row_ * LDW + kc]; \
            float4 mb_ = *(const float4*)&Ms[row_ * LDW + kc + 4]; \
            float4 xa_ = *(const float4*)&Xs[row_ * LDW + kc]; \
            float4 xb_ = *(const float4*)&Xs[row_ * LDW + kc + 4]; \
            ACC.x += DOT4(ma_,wl[0][0])+DOT4(mb_,wl[0][1])+DOT4(xa_,wr[0][0])+DOT4(xb_,wr[0][1]); \
            ACC.y += DOT4(ma_,wl[1][0])+DOT4(mb_,wl[1][1])+DOT4(xa_,wr[1][0])+DOT4(xb_,wr[1][1]); \
            ACC.z += DOT4(ma_,wl[2][0])+DOT4(mb_,wl[2][1])+DOT4(xa_,wr[2][0])+DOT4(xb_,wr[2][1]); \
            ACC.w += DOT4(ma_,wl[3][0])+DOT4(mb_,wl[3][1])+DOT4(xa_,wr[3][0])+DOT4(xb_,wr[3][1]); }
            SROW(0, acc0) SROW(1, acc1) SROW(2, acc2) SROW(3, acc3)
#undef SROW
        }
        if (do_relu) {
            acc0.x = fmaxf(acc0.x, 0.f); acc0.y = fmaxf(acc0.y, 0.f); acc0.z = fmaxf(acc0.z, 0.f); acc0.w = fmaxf(acc0.w, 0.f);
            acc1.x = fmaxf(acc1.x, 0.f); acc1.y = fmaxf(acc1.y, 0.f); acc1.z = fmaxf(acc1.z, 0.f); acc1.w = fmaxf(acc1.w, 0.f);
            acc2.x = fmaxf(acc2.x, 0.f); acc2.y = fmaxf(acc2.y, 0.f); acc2.z = fmaxf(acc2.z, 0.f); acc2.w = fmaxf(acc2.w, 0.f);
            acc3.x = fmaxf(acc3.x, 0.f); acc3.y = fmaxf(acc3.y, 0.f); acc3.z = fmaxf(acc3.z, 0.f); acc3.w = fmaxf(acc3.w, 0.f);
        }
        {
            int r0_ = rc0 + rgrp;
            if (r0_ < n)      *(float4*)(out + (size_t)r0_ * DD + cb) = acc0;
            if (r0_ + 16 < n) *(float4*)(out + (size_t)(r0_ + 16) * DD + cb) = acc1;
            if (r0_ + 32 < n) *(float4*)(out + (size_t)(r0_ + 32) * DD + cb) = acc2;
            if (r0_ + 48 < n) *(float4*)(out + (size_t)(r0_ + 48) * DD + cb) = acc3;
        }
    }
}

// -------------------- fused decoder layer-1 precompute (LDS-staged) --------
__global__ __launch_bounds__(256, 2)
void pre_fused_kernel(const float* __restrict__ hu, const float* __restrict__ hr,
                      const float* __restrict__ dW1, const float* __restrict__ db1,
                      float* __restrict__ P_u, float* __restrict__ P_r) {
    __shared__ __attribute__((aligned(16))) float Ws[DD * LDW];
    __shared__ __attribute__((aligned(16))) float Xs[64 * LDW];
    __shared__ float bsh[DD];
    int side = (blockIdx.x < NBU) ? 0 : 1;   // 0 = user (koff 0, bias), 1 = rest
    int koff = side ? DD : 0;
    const float* h; float* out; int n; int blk;
    if (side == 0) { h = hu; out = P_u; n = NU; blk = blockIdx.x; }
    else { h = hr; out = P_r; n = NR; blk = blockIdx.x - NBU; }
    int tid = threadIdx.x;
    for (int i = tid; i < DD * DD; i += 256) {
        int c = i >> 6, k = i & 63;
        Ws[c * LDW + k] = dW1[c * 2 * DD + koff + k];
    }
    if (tid < DD) bsh[tid] = side ? 0.f : db1[tid];
    int rgrp = tid & 15;
    int cgrp = tid >> 4;
    int cb = cgrp * 4;
    int r00 = blk * 256;
    for (int ch = 0; ch < 4; ch++) {
        int rc0 = r00 + ch * 64;
        __syncthreads();
        for (int i = tid; i < 1024; i += 256) {
            int row = i >> 4;
            int c4 = (i & 15) << 2;
            int gr = min(rc0 + row, n - 1);
            *(float4*)&Xs[row * LDW + c4] = *(const float4*)(h + (size_t)gr * DD + c4);
        }
        __syncthreads();
        float4 bias = {bsh[cb], bsh[cb + 1], bsh[cb + 2], bsh[cb + 3]};
        float4 acc0 = bias, acc1 = bias, acc2 = bias, acc3 = bias;
#pragma unroll 1
        for (int kc = 0; kc < DD; kc += 8) {
            float4 wv[4][2];
#pragma unroll
            for (int c = 0; c < 4; c++) {
                wv[c][0] = *(const float4*)&Ws[(cb + c) * LDW + kc];
                wv[c][1] = *(const float4*)&Ws[(cb + c) * LDW + kc + 4];
            }
#define PROW(J, ACC) { \
            int row_ = rgrp + 16 * (J); \
            float4 xa_ = *(const float4*)&Xs[row_ * LDW + kc]; \
            float4 xb_ = *(const float4*)&Xs[row_ * LDW + kc + 4]; \
            ACC.x += DOT4(xa_,wv[0][0])+DOT4(xb_,wv[0][1]); \
            ACC.y += DOT4(xa_,wv[1][0])+DOT4(xb_,wv[1][1]); \
            ACC.z += DOT4(xa_,wv[2][0])+DOT4(xb_,wv[2][1]); \
            ACC.w += DOT4(xa_,wv[3][0])+DOT4(xb_,wv[3][1]); }
            PROW(0, acc0) PROW(1, acc1) PROW(2, acc2) PROW(3, acc3)
#undef PROW
        }
        {
            int r0_ = rc0 + rgrp;
            if (r0_ < n)      *(float4*)(out + (size_t)r0_ * DD + cb) = acc0;
            if (r0_ + 16 < n) *(float4*)(out + (size_t)(r0_ + 16) * DD + cb) = acc1;
            if (r0_ + 32 < n) *(float4*)(out + (size_t)(r0_ + 32) * DD + cb) = acc2;
            if (r0_ + 48 < n) *(float4*)(out + (size_t)(r0_ + 48) * DD + cb) = acc3;
        }
    }
}

// -------------------- qbin: bin queries by 448-row Pu window ---------------
__global__ __launch_bounds__(256)
void qbin_kernel(const int* __restrict__ el_row, const int* __restrict__ el_col,
                 int* __restrict__ qcur, int2* __restrict__ qpairs) {
    __shared__ int2 stg[QB_E];            // 32KB
    __shared__ unsigned short gstg[QB_E]; // 8KB
    __shared__ int hist[512];
    __shared__ int sca[256], scb[256];
    __shared__ int gbase[512];
    __shared__ int gpos[512];
    int tid = threadIdx.x;
    hist[tid] = 0; hist[tid + 256] = 0;
    __syncthreads();
    int base = blockIdx.x * QB_E;
    int myg[16]; int myrank[16]; int2 myp[16];
#pragma unroll
    for (int i = 0; i < 16; i++) {
        int e = base + i * 256 + tid;
        if (e < NQ) {
            int row = el_row[e];
            int col = el_col[e];
            int g = row / QWIN;              // const-div -> magic mul
            int rowl = row - g * QWIN;
            myg[i] = g;
            myp[i] = make_int2((rowl << 16) | col, e);
            myrank[i] = atomicAdd(&hist[g], 1);
        } else myg[i] = -1;
    }
    __syncthreads();
    int b0 = tid * 2;
    int h0 = hist[b0], h1 = hist[b0 + 1];
    int run = h0 + h1;
    sca[tid] = run;
    __syncthreads();
    int* cur = sca; int* alt = scb;
    for (int off = 1; off < 256; off <<= 1) {
        int x = cur[tid];
        if (tid >= off) x += cur[tid - off];
        alt[tid] = x;
        __syncthreads();
        int* tmp = cur; cur = alt; alt = tmp;
    }
    int texcl = cur[tid] - run;
    gbase[b0] = texcl;
    gbase[b0 + 1] = texcl + h0;
    if (b0 < NQW && h0 > 0) gpos[b0] = atomicAdd(&qcur[b0], h0);
    if (b0 + 1 < NQW && h1 > 0) gpos[b0 + 1] = atomicAdd(&qcur[b0 + 1], h1);
    __syncthreads();
#pragma unroll
    for (int i = 0; i < 16; i++) {
        if (myg[i] >= 0) {
            int p = gbase[myg[i]] + myrank[i];
            stg[p] = myp[i];
            gstg[p] = (unsigned short)myg[i];
        }
    }
    __syncthreads();
    int tot = cur[255];
    for (int i = tid; i < tot; i += 256) {
        int g = gstg[i];
        int o = g * QCAP + gpos[g] + (i - gbase[g]);
        qpairs[o] = stg[i];
    }
}

// -------------------- qdec2: binned thread-per-query decoder ---------------
// One block per 448-row Pu window; queries of the window processed by 512
// threads, one query each (old proven decoder body). The block's Pu slice
// (114KB) becomes L2-resident on its XCD -> Pu fetched ~once chip-wide.
#define ZCOMB(Zi, i) float4 Zi; { float4 u_ = pu[i]; float4 v_ = pr[i]; \
    Zi.x = fmaxf(u_.x + v_.x, 0.f); Zi.y = fmaxf(u_.y + v_.y, 0.f); \
    Zi.z = fmaxf(u_.z + v_.z, 0.f); Zi.w = fmaxf(u_.w + v_.w, 0.f); }

__global__ __launch_bounds__(512, 2)
void qdec2_kernel(const float* __restrict__ Pu, const float* __restrict__ Pr,
                  const int2* __restrict__ qpairs, const int* __restrict__ qcur,
                  const float* __restrict__ dW2, const float* __restrict__ db2,
                  const float* __restrict__ dW3, const float* __restrict__ db3,
                  float* __restrict__ out) {
    __shared__ float W2s[DD * DD];
    __shared__ float b2s[DD], w3s[DD];
    int w = blockIdx.x;
    int tid = threadIdx.x;
    for (int i = tid; i < DD * DD; i += 512) W2s[i] = dW2[i];
    if (tid < DD) {
        b2s[tid] = db2[tid];
        w3s[tid] = dW3[tid];
    }
    __syncthreads();
    int tot = qcur[w];
    int r0 = w * QWIN;
    float db3v = db3[0];
    const int2* qp = qpairs + (size_t)w * QCAP;
    for (int qi = tid; qi < tot; qi += 512) {
        int2 p = qp[qi];
        int rowl = p.x >> 16;
        int col = p.x & 0xFFFF;
        const float4* pu = (const float4*)(Pu + (size_t)(r0 + rowl) * DD);
        const float4* pr = (const float4*)(Pr + (size_t)col * DD);
        ZCOMB(z0, 0)  ZCOMB(z1, 1)  ZCOMB(z2, 2)  ZCOMB(z3, 3)
        ZCOMB(z4, 4)  ZCOMB(z5, 5)  ZCOMB(z6, 6)  ZCOMB(z7, 7)
        ZCOMB(z8, 8)  ZCOMB(z9, 9)  ZCOMB(z10, 10) ZCOMB(z11, 11)
        ZCOMB(z12, 12) ZCOMB(z13, 13) ZCOMB(z14, 14) ZCOMB(z15, 15)
        float o = db3v;
#pragma unroll 2
        for (int c = 0; c < DD; c++) {
            const float4* wp = (const float4*)(W2s + c * DD);  // wave-broadcast
            float s = b2s[c]
                + DOT4(z0, wp[0])  + DOT4(z1, wp[1])  + DOT4(z2, wp[2])  + DOT4(z3, wp[3])
                + DOT4(z4, wp[4])  + DOT4(z5, wp[5])  + DOT4(z6, wp[6])  + DOT4(z7, wp[7])
                + DOT4(z8, wp[8])  + DOT4(z9, wp[9])  + DOT4(z10, wp[10]) + DOT4(z11, wp[11])
                + DOT4(z12, wp[12]) + DOT4(z13, wp[13]) + DOT4(z14, wp[14]) + DOT4(z15, wp[15]);
            o += fmaxf(s, 0.f) * w3s[c];
        }
        out[p.y] = o;
    }
}

extern "C" void kernel_launch(void* const* d_in, const int* in_sizes, int n_in,
                              void* d_out, int out_size, void* d_ws, size_t ws_size,
                              hipStream_t stream) {
    const float* x_user = (const float*)d_in[0];
    const float* x_rest = (const float*)d_in[1];
    const float* Wl     = (const float*)d_in[2];
    const float* Wr     = (const float*)d_in[3];
    const float* bl     = (const float*)d_in[4];
    const float* dW1    = (const float*)d_in[5];
    const float* db1    = (const float*)d_in[6];
    const float* dW2    = (const float*)d_in[7];
    const float* db2    = (const float*)d_in[8];
    const float* dW3    = (const float*)d_in[9];
    const float* db3    = (const float*)d_in[10];
    const int* ur_src   = (const int*)d_in[11];
    const int* ur_dst   = (const int*)d_in[12];
    const int* ru_src   = (const int*)d_in[13];
    const int* ru_dst   = (const int*)d_in[14];
    const int* el_row   = (const int*)d_in[15];
    const int* el_col   = (const int*)d_in[16];
    float* out = (float*)d_out;

    char* w = (char*)d_ws;
    size_t off = 0;
    auto alloc = [&](size_t bytes) -> void* {
        void* p = (void*)(w + off);
        off += (bytes + 255) & ~(size_t)255;
        return p;
    };
    float* hu0    = (float*)alloc((size_t)NU * DD * 4);
    float* hu1    = (float*)alloc((size_t)NU * DD * 4);
    float* hr0    = (float*)alloc((size_t)NR * DD * 4);
    float* hr1    = (float*)alloc((size_t)NR * DD * 4);
    float* mean_u = (float*)alloc((size_t)NU * DD * 4);
    float* mean_r = (float*)alloc((size_t)NR * DD * 4);
    int* csr_u  = (int*)alloc((size_t)NE * 4);
    int* csr_r  = (int*)alloc((size_t)NE * 4);
    int* rs_u   = (int*)alloc((size_t)(NU + 1) * 4);
    int* rs_r   = (int*)alloc((size_t)(NR + 1) * 4);
    int* bcur   = (int*)alloc((size_t)2 * NBS * 4);   // 784 -> pads to 1024
    int* bbase  = (int*)alloc((size_t)2 * NBS * 4);   // 784 -> pads to 1024
    int* qcur   = (int*)alloc((size_t)512 * 4);       // 2048

    // pair buffer carved from mean_u (free until gather writes it):
    // build: 2*98*24576*8B = 38.5MB <= 51.2MB. decoder: qpairs 447*1536*8B=5.5MB
    int2* pairs = (int2*)mean_u;
    int2* qpairs = (int2*)mean_u;

    // ---- CSR build: bin by dst window -> window-local count/scan/fill ----
    // one memset zeroes bcur (1024) + bbase (1024) + qcur (2048)
    hipMemsetAsync(bcur, 0, 4096, stream);
    binpass_kernel<<<2 * NPBB, 256, 0, stream>>>(ru_src, ru_dst, ur_src, ur_dst,
                                                 bcur, pairs);
    bbase_kernel<<<2, 128, 0, stream>>>(bcur, bbase, rs_u, rs_r);
    fillpass_kernel<<<2 * NBS, 256, 0, stream>>>(pairs, bcur, bbase,
                                                 rs_u, rs_r, csr_u, csr_r);

    // ---- 3 SAGE layers: 2 fused launches per layer ----
    const float* cu = x_user;
    const float* cr = x_rest;
    float* nu_[3] = {hu0, hu1, hu0};
    float* nr_[3] = {hr0, hr1, hr0};
    const int ggrid = (NR + NU + 3) / 4;   // 62500

    for (int l = 0; l < 3; l++) {
        const float* Wl2 = Wl + (size_t)l * 2 * DD * DD;
        const float* Wr2 = Wr + (size_t)l * 2 * DD * DD;
        const float* bl2 = bl + (size_t)l * 2 * DD;
        int relu = (l < 2) ? 1 : 0;
        gather2_kernel<<<ggrid, 256, 0, stream>>>(cu, csr_r, rs_r, mean_r,
                                                  cr, csr_u, rs_u, mean_u);
        sage_fused_kernel<<<NBR + NBU, 256, 0, stream>>>(mean_r, cr, mean_u, cu,
                                                         Wl2, Wr2, bl2,
                                                         nr_[l], nu_[l], relu);
        cu = nu_[l];
        cr = nr_[l];
    }
    // ---- decoder: precompute P, bin queries by Pu window, binned decode ---
    float* P_u = hu1;
    float* P_r = hr1;
    pre_fused_kernel<<<NBU + NBR, 256, 0, stream>>>(cu, cr, dW1, db1, P_u, P_r);
    qbin_kernel<<<NQB, 256, 0, stream>>>(el_row, el_col, qcur, qpairs);
    qdec2_kernel<<<NQW, 512, 0, stream>>>(P_u, P_r, qpairs, qcur,
                                          dW2, db2, dW3, db3, out);
}

// Round 10
// 1015.703 us; speedup vs baseline: 1.1471x; 1.0194x over previous
//
#include <hip/hip_runtime.h>

#define NU 200000
#define NR 50000
#define DD 64
#define NE 2000000
#define NQ 500000
#define NBR 196   // ceil(NR/256)
#define NBU 782   // ceil(NU/256)
#define LDW 68    // padded LDS row stride (68*4B=272B: 16B-aligned, bank-shift 4)

// ---- dst-windowed CSR build parameters ----
#define NBS 98              // dst windows per side
#define BKT_CAP 24576       // pair capacity per window (mean 20480, +28 sigma)
#define LW_U 11             // 2048 users per window
#define LW_R 9              // 512 restaurants per window
#define PB_E 4096           // edges per binpass block
#define NPBB 489            // ceil(NE / PB_E)

// ---- binned decoder parameters ----
#define QWIN 448            // Pu rows per decoder window
#define NQW 447             // ceil(NU / QWIN)
#define QCAP 1536           // queries per window (mean 1120, +12 sigma)
#define QB_E 4096
#define NQB 123             // ceil(NQ / QB_E)

// -------------------- binpass: bin (src,dst) pairs by dst window -----------
__global__ __launch_bounds__(256)
void binpass_kernel(const int* __restrict__ ru_src, const int* __restrict__ ru_dst,
                    const int* __restrict__ ur_src, const int* __restrict__ ur_dst,
                    int* __restrict__ bcur, int2* __restrict__ pairs) {
    __shared__ int2 stg[PB_E];
    __shared__ unsigned char gstg[PB_E];
    __shared__ int hist[256];
    __shared__ int sca[256], scb[256];
    __shared__ int gpos[128];
    int side = (blockIdx.x >= NPBB) ? 1 : 0;
    int blk = side ? (blockIdx.x - NPBB) : blockIdx.x;
    const int* src = side ? ur_src : ru_src;
    const int* dst = side ? ur_dst : ru_dst;
    int lw = side ? LW_R : LW_U;
    int* bc = bcur + side * NBS;
    int2* region = pairs + (size_t)side * NBS * BKT_CAP;
    int tid = threadIdx.x;
    hist[tid] = 0;
    __syncthreads();
    int base = blk * PB_E;
    int myg[16]; int myrank[16]; int2 myp[16];
#pragma unroll
    for (int i = 0; i < 16; i++) {
        int e = base + i * 256 + tid;
        if (e < NE) {
            int d = dst[e];
            int g = d >> lw;
            myg[i] = g;
            myp[i] = make_int2(src[e], d);
            myrank[i] = atomicAdd(&hist[g], 1);
        } else myg[i] = -1;
    }
    __syncthreads();
    int h = hist[tid];
    sca[tid] = h;
    __syncthreads();
    int* cur = sca; int* alt = scb;
    for (int off = 1; off < 256; off <<= 1) {
        int x = cur[tid];
        if (tid >= off) x += cur[tid - off];
        alt[tid] = x;
        __syncthreads();
        int* tmp = cur; cur = alt; alt = tmp;
    }
    alt[tid] = cur[tid] - h;          // exclusive base per bucket
    if (tid < NBS && h > 0) gpos[tid] = atomicAdd(&bc[tid], h);
    __syncthreads();
    int* basep = alt;
#pragma unroll
    for (int i = 0; i < 16; i++) {
        if (myg[i] >= 0) {
            int p = basep[myg[i]] + myrank[i];
            stg[p] = myp[i];
            gstg[p] = (unsigned char)myg[i];
        }
    }
    __syncthreads();
    int tot = cur[255];
    for (int i = tid; i < tot; i += 256) {
        int g = gstg[i];
        int o = g * BKT_CAP + gpos[g] + (i - basep[g]);
        region[o] = stg[i];
    }
}

// -------------------- bbase: scan 98 window totals per side ----------------
__global__ void bbase_kernel(const int* __restrict__ bcur, int* __restrict__ bbase,
                             int* __restrict__ rs_u, int* __restrict__ rs_r) {
    __shared__ int a[128], b[128];
    int sidx = blockIdx.x;
    const int* bc = bcur + sidx * NBS;
    int* bb = bbase + sidx * NBS;
    int tid = threadIdx.x;
    a[tid] = (tid < NBS) ? bc[tid] : 0;
    __syncthreads();
    int* cur = a; int* alt = b;
    for (int off = 1; off < 128; off <<= 1) {
        int t = cur[tid];
        if (tid >= off) t += cur[tid - off];
        alt[tid] = t;
        __syncthreads();
        int* tmp = cur; cur = alt; alt = tmp;
    }
    if (tid < NBS) bb[tid] = (tid == 0) ? 0 : cur[tid - 1];
    if (tid == 0) { if (sidx == 0) rs_u[NU] = NE; else rs_r[NR] = NE; }
}

// -------------------- fillpass: per-window count/scan/scatter in LDS -------
__global__ __launch_bounds__(256)
void fillpass_kernel(const int2* __restrict__ pairs, const int* __restrict__ bcur,
                     const int* __restrict__ bbase,
                     int* __restrict__ rs_u, int* __restrict__ rs_r,
                     int* __restrict__ csr_u, int* __restrict__ csr_r) {
    __shared__ int win[BKT_CAP];      // 96 KB CSR window image
    __shared__ int lcnt[2048];        // 8 KB
    __shared__ int lofs[2048];        // 8 KB
    __shared__ int tsc[256], tsc2[256];
    int side = (blockIdx.x >= NBS) ? 1 : 0;
    int bkt = side ? (blockIdx.x - NBS) : blockIdx.x;
    const int2* reg = pairs + ((size_t)side * NBS + bkt) * BKT_CAP;
    int* rs = side ? rs_r : rs_u;
    int* csr = side ? csr_r : csr_u;
    int W = side ? 512 : 2048;
    int lw = side ? LW_R : LW_U;
    int n = side ? NR : NU;
    int d0 = bkt << lw;
    int tot = bcur[side * NBS + bkt];
    int base = bbase[side * NBS + bkt];
    int tid = threadIdx.x;
    for (int i = tid; i < W; i += 256) lcnt[i] = 0;
    __syncthreads();
    // pass 1: local degree count
    for (int i = tid; i < tot; i += 256) {
        int2 p = reg[i];
        atomicAdd(&lcnt[p.y - d0], 1);
    }
    __syncthreads();
    // exclusive scan of W counters (thread-chunked + block scan)
    int per = W >> 8;                 // 8 (user) or 2 (rest)
    int b0 = tid * per;
    int run = 0;
    for (int i = 0; i < per; i++) { int v = lcnt[b0 + i]; lofs[b0 + i] = run; run += v; }
    tsc[tid] = run;
    __syncthreads();
    int* cur = tsc; int* alt = tsc2;
    for (int off = 1; off < 256; off <<= 1) {
        int x = cur[tid];
        if (tid >= off) x += cur[tid - off];
        alt[tid] = x;
        __syncthreads();
        int* tmp = cur; cur = alt; alt = tmp;
    }
    int texcl = cur[tid] - run;
    for (int i = 0; i < per; i++) lofs[b0 + i] += texcl;
    __syncthreads();
    // write rs window (coalesced)
    int wn = min(W, n - d0);
    for (int i = tid; i < wn; i += 256) rs[d0 + i] = base + lofs[i];
    __syncthreads();
    // pass 2: slot assignment via LDS cursor + LDS scatter
    for (int i = tid; i < tot; i += 256) {
        int2 p = reg[i];
        int slot = atomicAdd(&lofs[p.y - d0], 1);
        win[slot] = p.x;
    }
    __syncthreads();
    // stream out (coalesced)
    for (int i = tid; i < tot; i += 256) csr[base + i] = win[i];
}

// -------------------- fused gather mean: wave per dst row, 16x4 groups -----
// (R6 form: 2-deep float4 loads — measured best; 4-deep regressed.)
__global__ __launch_bounds__(256)
void gather2_kernel(const float* __restrict__ hu, const int* __restrict__ csr_r,
                    const int* __restrict__ rs_r, float* __restrict__ mean_r,
                    const float* __restrict__ hr, const int* __restrict__ csr_u,
                    const int* __restrict__ rs_u, float* __restrict__ mean_u) {
    int lane = threadIdx.x & 63;
    int wave = blockIdx.x * 4 + (threadIdx.x >> 6);
    const float* h; const int* csr; const int* rs; float* mean; int r;
    if (wave < NR) { h = hu; csr = csr_r; rs = rs_r; mean = mean_r; r = wave; }
    else if (wave < NR + NU) { h = hr; csr = csr_u; rs = rs_u; mean = mean_u; r = wave - NR; }
    else return;
    int s = rs[r], e = rs[r + 1];
    int g = lane >> 4;            // neighbor subgroup 0..3
    int fo = (lane & 15) << 2;    // feature offset 0,4,...,60
    float4 a0 = {0.f, 0.f, 0.f, 0.f};
    float4 a1 = {0.f, 0.f, 0.f, 0.f};
    for (int j = s; j < e; j += 64) {
        int rem = e - j;
        int nch = rem < 64 ? rem : 64;
        int li = lane < nch ? lane : nch - 1;
        int idx = csr[j + li];
        for (int kk = 0; kk < nch; kk += 8) {
            int j0 = kk + g;          // <= 59
            int j1 = kk + 4 + g;      // <= 63
            int i0 = __shfl(idx, j0);
            int i1 = __shfl(idx, j1);
            float4 x0 = *(const float4*)(h + (size_t)i0 * DD + fo);
            float4 x1 = *(const float4*)(h + (size_t)i1 * DD + fo);
            if (j0 < nch) { a0.x += x0.x; a0.y += x0.y; a0.z += x0.z; a0.w += x0.w; }
            if (j1 < nch) { a1.x += x1.x; a1.y += x1.y; a1.z += x1.z; a1.w += x1.w; }
        }
    }
    float4 acc;
    acc.x = a0.x + a1.x; acc.y = a0.y + a1.y;
    acc.z = a0.z + a1.z; acc.w = a0.w + a1.w;
    acc.x += __shfl_xor(acc.x, 16); acc.y += __shfl_xor(acc.y, 16);
    acc.z += __shfl_xor(acc.z, 16); acc.w += __shfl_xor(acc.w, 16);
    acc.x += __shfl_xor(acc.x, 32); acc.y += __shfl_xor(acc.y, 32);
    acc.z += __shfl_xor(acc.z, 32); acc.w += __shfl_xor(acc.w, 32);
    if (g == 0) {
        float inv = 1.0f / fmaxf((float)(e - s), 1.0f);
        acc.x *= inv; acc.y *= inv; acc.z *= inv; acc.w *= inv;
        *(float4*)(mean + (size_t)r * DD + fo) = acc;
    }
}

#define DOT4(A, B) ((A).x*(B).x + (A).y*(B).y + (A).z*(B).z + (A).w*(B).w)

// -------------------- fused SAGE linear: LDS-staged row tiles --------------
__global__ __launch_bounds__(256, 2)
void sage_fused_kernel(const float* __restrict__ mean_r, const float* __restrict__ hr,
                       const float* __restrict__ mean_u, const float* __restrict__ hu,
                       const float* __restrict__ Wl2, const float* __restrict__ Wr2,
                       const float* __restrict__ bl2,
                       float* __restrict__ out_r, float* __restrict__ out_u, int do_relu) {
    __shared__ __attribute__((aligned(16))) float Wls[DD * LDW];
    __shared__ __attribute__((aligned(16))) float Wrs[DD * LDW];
    __shared__ __attribute__((aligned(16))) float Ms[64 * LDW];
    __shared__ __attribute__((aligned(16))) float Xs[64 * LDW];
    __shared__ float bsh[DD];
    int side = (blockIdx.x < NBR) ? 0 : 1;
    const float* Wl = Wl2 + side * DD * DD;
    const float* Wr = Wr2 + side * DD * DD;
    const float* bl = bl2 + side * DD;
    const float* mean; const float* h; float* out; int n; int blk;
    if (side == 0) { mean = mean_r; h = hr; out = out_r; n = NR; blk = blockIdx.x; }
    else { mean = mean_u; h = hu; out = out_u; n = NU; blk = blockIdx.x - NBR; }
    int tid = threadIdx.x;
    for (int i = tid; i < DD * DD; i += 256) {
        int c = i >> 6, k = i & 63;
        Wls[c * LDW + k] = Wl[i];
        Wrs[c * LDW + k] = Wr[i];
    }
    if (tid < DD) bsh[tid] = bl[tid];
    int rgrp = tid & 15;
    int cgrp = tid >> 4;
    int cb = cgrp * 4;
    int r00 = blk * 256;
    for (int ch = 0; ch < 4; ch++) {
        int rc0 = r00 + ch * 64;
        __syncthreads();   // LDS reuse guard (also covers W load on ch=0)
        for (int i = tid; i < 1024; i += 256) {
            int row = i >> 4;
            int c4 = (i & 15) << 2;
            int gr = min(rc0 + row, n - 1);
            *(float4*)&Ms[row * LDW + c4] = *(const float4*)(mean + (size_t)gr * DD + c4);
            *(float4*)&Xs[row * LDW + c4] = *(const float4*)(h + (size_t)gr * DD + c4);
        }
        __syncthreads();
        float4 bias = {bsh[cb], bsh[cb + 1], bsh[cb + 2], bsh[cb + 3]};
        float4 acc0 = bias, acc1 = bias, acc2 = bias, acc3 = bias;
#pragma unroll 1
        for (int kc = 0; kc < DD; kc += 8) {
            float4 wl[4][2], wr[4][2];
#pragma unroll
            for (int c = 0; c < 4; c++) {
                wl[c][0] = *(const float4*)&Wls[(cb + c) * LDW + kc];
                wl[c][1] = *(const float4*)&Wls[(cb + c) * LDW + kc + 4];
                wr[c][0] = *(const float4*)&Wrs[(cb + c) * LDW + kc];
                wr[c][1] = *(const float4*)&Wrs[(cb + c) * LDW + kc + 4];
            }
#define SROW(J, ACC) { \
            int row_ = rgrp + 16 * (J); \
            float4 ma_ = *(const float4*)&Ms[row_ * LDW + kc]; \
            float4 mb_ = *(const float4*)&Ms[row_ * LDW + kc + 4]; \
            float4 xa_ = *(const float4*)&Xs[row_ * LDW + kc]; \
            float4 xb_ = *(const float4*)&Xs[row_ * LDW + kc + 4]; \
            ACC.x += DOT4(ma_,wl[0][0])+DOT4(mb_,wl[0][1])+DOT4(xa_,wr[0][0])+DOT4(xb_,wr[0][1]); \
            ACC.y += DOT4(ma_,wl[1][0])+DOT4(mb_,wl[1][1])+DOT4(xa_,wr[1][0])+DOT4(xb_,wr[1][1]); \
            ACC.z += DOT4(ma_,wl[2][0])+DOT4(mb_,wl[2][1])+DOT4(xa_,wr[2][0])+DOT4(xb_,wr[2][1]); \
            ACC.w += DOT4(ma_,wl[3][0])+DOT4(mb_,wl[3][1])+DOT4(xa_,wr[3][0])+DOT4(xb_,wr[3][1]); }
            SROW(0, acc0) SROW(1, acc1) SROW(2, acc2) SROW(3, acc3)
#undef SROW
        }
        if (do_relu) {
            acc0.x = fmaxf(acc0.x, 0.f); acc0.y = fmaxf(acc0.y, 0.f); acc0.z = fmaxf(acc0.z, 0.f); acc0.w = fmaxf(acc0.w, 0.f);
            acc1.x = fmaxf(acc1.x, 0.f); acc1.y = fmaxf(acc1.y, 0.f); acc1.z = fmaxf(acc1.z, 0.f); acc1.w = fmaxf(acc1.w, 0.f);
            acc2.x = fmaxf(acc2.x, 0.f); acc2.y = fmaxf(acc2.y, 0.f); acc2.z = fmaxf(acc2.z, 0.f); acc2.w = fmaxf(acc2.w, 0.f);
            acc3.x = fmaxf(acc3.x, 0.f); acc3.y = fmaxf(acc3.y, 0.f); acc3.z = fmaxf(acc3.z, 0.f); acc3.w = fmaxf(acc3.w, 0.f);
        }
        {
            int r0_ = rc0 + rgrp;
            if (r0_ < n)      *(float4*)(out + (size_t)r0_ * DD + cb) = acc0;
            if (r0_ + 16 < n) *(float4*)(out + (size_t)(r0_ + 16) * DD + cb) = acc1;
            if (r0_ + 32 < n) *(float4*)(out + (size_t)(r0_ + 32) * DD + cb) = acc2;
            if (r0_ + 48 < n) *(float4*)(out + (size_t)(r0_ + 48) * DD + cb) = acc3;
        }
    }
}

// -------------------- fused decoder layer-1 precompute (LDS-staged) --------
__global__ __launch_bounds__(256, 2)
void pre_fused_kernel(const float* __restrict__ hu, const float* __restrict__ hr,
                      const float* __restrict__ dW1, const float* __restrict__ db1,
                      float* __restrict__ P_u, float* __restrict__ P_r) {
    __shared__ __attribute__((aligned(16))) float Ws[DD * LDW];
    __shared__ __attribute__((aligned(16))) float Xs[64 * LDW];
    __shared__ float bsh[DD];
    int side = (blockIdx.x < NBU) ? 0 : 1;   // 0 = user (koff 0, bias), 1 = rest
    int koff = side ? DD : 0;
    const float* h; float* out; int n; int blk;
    if (side == 0) { h = hu; out = P_u; n = NU; blk = blockIdx.x; }
    else { h = hr; out = P_r; n = NR; blk = blockIdx.x - NBU; }
    int tid = threadIdx.x;
    for (int i = tid; i < DD * DD; i += 256) {
        int c = i >> 6, k = i & 63;
        Ws[c * LDW + k] = dW1[c * 2 * DD + koff + k];
    }
    if (tid < DD) bsh[tid] = side ? 0.f : db1[tid];
    int rgrp = tid & 15;
    int cgrp = tid >> 4;
    int cb = cgrp * 4;
    int r00 = blk * 256;
    for (int ch = 0; ch < 4; ch++) {
        int rc0 = r00 + ch * 64;
        __syncthreads();
        for (int i = tid; i < 1024; i += 256) {
            int row = i >> 4;
            int c4 = (i & 15) << 2;
            int gr = min(rc0 + row, n - 1);
            *(float4*)&Xs[row * LDW + c4] = *(const float4*)(h + (size_t)gr * DD + c4);
        }
        __syncthreads();
        float4 bias = {bsh[cb], bsh[cb + 1], bsh[cb + 2], bsh[cb + 3]};
        float4 acc0 = bias, acc1 = bias, acc2 = bias, acc3 = bias;
#pragma unroll 1
        for (int kc = 0; kc < DD; kc += 8) {
            float4 wv[4][2];
#pragma unroll
            for (int c = 0; c < 4; c++) {
                wv[c][0] = *(const float4*)&Ws[(cb + c) * LDW + kc];
                wv[c][1] = *(const float4*)&Ws[(cb + c) * LDW + kc + 4];
            }
#define PROW(J, ACC) { \
            int row_ = rgrp + 16 * (J); \
            float4 xa_ = *(const float4*)&Xs[row_ * LDW + kc]; \
            float4 xb_ = *(const float4*)&Xs[row_ * LDW + kc + 4]; \
            ACC.x += DOT4(xa_,wv[0][0])+DOT4(xb_,wv[0][1]); \
            ACC.y += DOT4(xa_,wv[1][0])+DOT4(xb_,wv[1][1]); \
            ACC.z += DOT4(xa_,wv[2][0])+DOT4(xb_,wv[2][1]); \
            ACC.w += DOT4(xa_,wv[3][0])+DOT4(xb_,wv[3][1]); }
            PROW(0, acc0) PROW(1, acc1) PROW(2, acc2) PROW(3, acc3)
#undef PROW
        }
        {
            int r0_ = rc0 + rgrp;
            if (r0_ < n)      *(float4*)(out + (size_t)r0_ * DD + cb) = acc0;
            if (r0_ + 16 < n) *(float4*)(out + (size_t)(r0_ + 16) * DD + cb) = acc1;
            if (r0_ + 32 < n) *(float4*)(out + (size_t)(r0_ + 32) * DD + cb) = acc2;
            if (r0_ + 48 < n) *(float4*)(out + (size_t)(r0_ + 48) * DD + cb) = acc3;
        }
    }
}

// -------------------- qbin: bin queries by 448-row Pu window ---------------
__global__ __launch_bounds__(256)
void qbin_kernel(const int* __restrict__ el_row, const int* __restrict__ el_col,
                 int* __restrict__ qcur, int2* __restrict__ qpairs) {
    __shared__ int2 stg[QB_E];            // 32KB
    __shared__ unsigned short gstg[QB_E]; // 8KB
    __shared__ int hist[512];
    __shared__ int sca[256], scb[256];
    __shared__ int gbase[512];
    __shared__ int gpos[512];
    int tid = threadIdx.x;
    hist[tid] = 0; hist[tid + 256] = 0;
    __syncthreads();
    int base = blockIdx.x * QB_E;
    int myg[16]; int myrank[16]; int2 myp[16];
#pragma unroll
    for (int i = 0; i < 16; i++) {
        int e = base + i * 256 + tid;
        if (e < NQ) {
            int row = el_row[e];
            int col = el_col[e];
            int g = row / QWIN;              // const-div -> magic mul
            int rowl = row - g * QWIN;
            myg[i] = g;
            myp[i] = make_int2((rowl << 16) | col, e);
            myrank[i] = atomicAdd(&hist[g], 1);
        } else myg[i] = -1;
    }
    __syncthreads();
    int b0 = tid * 2;
    int h0 = hist[b0], h1 = hist[b0 + 1];
    int run = h0 + h1;
    sca[tid] = run;
    __syncthreads();
    int* cur = sca; int* alt = scb;
    for (int off = 1; off < 256; off <<= 1) {
        int x = cur[tid];
        if (tid >= off) x += cur[tid - off];
        alt[tid] = x;
        __syncthreads();
        int* tmp = cur; cur = alt; alt = tmp;
    }
    int texcl = cur[tid] - run;
    gbase[b0] = texcl;
    gbase[b0 + 1] = texcl + h0;
    if (b0 < NQW && h0 > 0) gpos[b0] = atomicAdd(&qcur[b0], h0);
    if (b0 + 1 < NQW && h1 > 0) gpos[b0 + 1] = atomicAdd(&qcur[b0 + 1], h1);
    __syncthreads();
#pragma unroll
    for (int i = 0; i < 16; i++) {
        if (myg[i] >= 0) {
            int p = gbase[myg[i]] + myrank[i];
            stg[p] = myp[i];
            gstg[p] = (unsigned short)myg[i];
        }
    }
    __syncthreads();
    int tot = cur[255];
    for (int i = tid; i < tot; i += 256) {
        int g = gstg[i];
        int o = g * QCAP + gpos[g] + (i - gbase[g]);
        qpairs[o] = stg[i];
    }
}

// -------------------- qdec3: binned register-tiled GEMM decoder ------------
// 2 half-blocks per window; per 64-query chunk: stage Z=relu(Pu+Pr) in LDS,
// sage-style 4row x 4col register tile vs LDS W2, then relu*w3 row-reduce.
__global__ __launch_bounds__(256)
void qdec3_kernel(const float* __restrict__ Pu, const float* __restrict__ Pr,
                  const int2* __restrict__ qpairs, const int* __restrict__ qcur,
                  const float* __restrict__ dW2, const float* __restrict__ db2,
                  const float* __restrict__ dW3, const float* __restrict__ db3,
                  float* __restrict__ out) {
    __shared__ __attribute__((aligned(16))) float W2s[DD * LDW];
    __shared__ __attribute__((aligned(16))) float Zs[64 * LDW];
    __shared__ float red[64 * 17];
    __shared__ float bsh[DD], w3s[DD];
    __shared__ int2 qrow[64];
    int w = blockIdx.x >> 1;
    int half = blockIdx.x & 1;
    int tid = threadIdx.x;
    for (int i = tid; i < DD * DD; i += 256) {
        int c = i >> 6, k = i & 63;
        W2s[c * LDW + k] = dW2[i];
    }
    if (tid < DD) { bsh[tid] = db2[tid]; w3s[tid] = dW3[tid]; }
    int tot = qcur[w];
    int r0 = w * QWIN;
    float db3v = db3[0];
    const int2* qp = qpairs + (size_t)w * QCAP;
    int rgrp = tid & 15;
    int cgrp = tid >> 4;
    int cb = cgrp * 4;
    for (int q0 = half * 64; q0 < tot; q0 += 128) {
        int cnt = min(64, tot - q0);
        __syncthreads();              // guards W2s (1st iter) + Zs/qrow reuse
        if (tid < 64) qrow[tid] = qp[q0 + min(tid, cnt - 1)];
        __syncthreads();
        // stage Z = relu(Pu_row + Pr_row)
        for (int i = tid; i < 1024; i += 256) {
            int row = i >> 4, c4 = (i & 15) << 2;
            int2 p = qrow[row];
            float4 u = *(const float4*)(Pu + (size_t)(r0 + (p.x >> 16)) * DD + c4);
            float4 v = *(const float4*)(Pr + (size_t)(p.x & 0xFFFF) * DD + c4);
            float4 z;
            z.x = fmaxf(u.x + v.x, 0.f); z.y = fmaxf(u.y + v.y, 0.f);
            z.z = fmaxf(u.z + v.z, 0.f); z.w = fmaxf(u.w + v.w, 0.f);
            *(float4*)&Zs[row * LDW + c4] = z;
        }
        __syncthreads();
        float4 bias = {bsh[cb], bsh[cb + 1], bsh[cb + 2], bsh[cb + 3]};
        float4 acc0 = bias, acc1 = bias, acc2 = bias, acc3 = bias;
#pragma unroll 1
        for (int kc = 0; kc < DD; kc += 8) {
            float4 wv[4][2];
#pragma unroll
            for (int c = 0; c < 4; c++) {
                wv[c][0] = *(const float4*)&W2s[(cb + c) * LDW + kc];
                wv[c][1] = *(const float4*)&W2s[(cb + c) * LDW + kc + 4];
            }
#define QROW(J, ACC) { \
            int row_ = rgrp + 16 * (J); \
            float4 xa_ = *(const float4*)&Zs[row_ * LDW + kc]; \
            float4 xb_ = *(const float4*)&Zs[row_ * LDW + kc + 4]; \
            ACC.x += DOT4(xa_,wv[0][0])+DOT4(xb_,wv[0][1]); \
            ACC.y += DOT4(xa_,wv[1][0])+DOT4(xb_,wv[1][1]); \
            ACC.z += DOT4(xa_,wv[2][0])+DOT4(xb_,wv[2][1]); \
            ACC.w += DOT4(xa_,wv[3][0])+DOT4(xb_,wv[3][1]); }
            QROW(0, acc0) QROW(1, acc1) QROW(2, acc2) QROW(3, acc3)
#undef QROW
        }
        // per-row partial: dot(relu(S_row), w3) over this thread's 4 cols
        float4 w3v = {w3s[cb], w3s[cb + 1], w3s[cb + 2], w3s[cb + 3]};
        red[(rgrp +  0) * 17 + cgrp] =
            fmaxf(acc0.x, 0.f) * w3v.x + fmaxf(acc0.y, 0.f) * w3v.y +
            fmaxf(acc0.z, 0.f) * w3v.z + fmaxf(acc0.w, 0.f) * w3v.w;
        red[(rgrp + 16) * 17 + cgrp] =
            fmaxf(acc1.x, 0.f) * w3v.x + fmaxf(acc1.y, 0.f) * w3v.y +
            fmaxf(acc1.z, 0.f) * w3v.z + fmaxf(acc1.w, 0.f) * w3v.w;
        red[(rgrp + 32) * 17 + cgrp] =
            fmaxf(acc2.x, 0.f) * w3v.x + fmaxf(acc2.y, 0.f) * w3v.y +
            fmaxf(acc2.z, 0.f) * w3v.z + fmaxf(acc2.w, 0.f) * w3v.w;
        red[(rgrp + 48) * 17 + cgrp] =
            fmaxf(acc3.x, 0.f) * w3v.x + fmaxf(acc3.y, 0.f) * w3v.y +
            fmaxf(acc3.z, 0.f) * w3v.z + fmaxf(acc3.w, 0.f) * w3v.w;
        __syncthreads();
        if (tid < 64 && tid < cnt) {
            float s = db3v;
#pragma unroll
            for (int c = 0; c < 16; c++) s += red[tid * 17 + c];
            out[qrow[tid].y] = s;
        }
    }
}

extern "C" void kernel_launch(void* const* d_in, const int* in_sizes, int n_in,
                              void* d_out, int out_size, void* d_ws, size_t ws_size,
                              hipStream_t stream) {
    const float* x_user = (const float*)d_in[0];
    const float* x_rest = (const float*)d_in[1];
    const float* Wl     = (const float*)d_in[2];
    const float* Wr     = (const float*)d_in[3];
    const float* bl     = (const float*)d_in[4];
    const float* dW1    = (const float*)d_in[5];
    const float* db1    = (const float*)d_in[6];
    const float* dW2    = (const float*)d_in[7];
    const float* db2    = (const float*)d_in[8];
    const float* dW3    = (const float*)d_in[9];
    const float* db3    = (const float*)d_in[10];
    const int* ur_src   = (const int*)d_in[11];
    const int* ur_dst   = (const int*)d_in[12];
    const int* ru_src   = (const int*)d_in[13];
    const int* ru_dst   = (const int*)d_in[14];
    const int* el_row   = (const int*)d_in[15];
    const int* el_col   = (const int*)d_in[16];
    float* out = (float*)d_out;

    char* w = (char*)d_ws;
    size_t off = 0;
    auto alloc = [&](size_t bytes) -> void* {
        void* p = (void*)(w + off);
        off += (bytes + 255) & ~(size_t)255;
        return p;
    };
    float* hu0    = (float*)alloc((size_t)NU * DD * 4);
    float* hu1    = (float*)alloc((size_t)NU * DD * 4);
    float* hr0    = (float*)alloc((size_t)NR * DD * 4);
    float* hr1    = (float*)alloc((size_t)NR * DD * 4);
    float* mean_u = (float*)alloc((size_t)NU * DD * 4);
    float* mean_r = (float*)alloc((size_t)NR * DD * 4);
    int* csr_u  = (int*)alloc((size_t)NE * 4);
    int* csr_r  = (int*)alloc((size_t)NE * 4);
    int* rs_u   = (int*)alloc((size_t)(NU + 1) * 4);
    int* rs_r   = (int*)alloc((size_t)(NR + 1) * 4);
    int* bcur   = (int*)alloc((size_t)2 * NBS * 4);   // 784 -> pads to 1024
    int* bbase  = (int*)alloc((size_t)2 * NBS * 4);   // 784 -> pads to 1024
    int* qcur   = (int*)alloc((size_t)512 * 4);       // 2048

    // pair buffer carved from mean_u (free until gather writes it):
    // build: 2*98*24576*8B = 38.5MB <= 51.2MB. decoder: qpairs 447*1536*8B=5.5MB
    int2* pairs = (int2*)mean_u;
    int2* qpairs = (int2*)mean_u;

    // ---- CSR build: bin by dst window -> window-local count/scan/fill ----
    // one memset zeroes bcur (1024) + bbase (1024) + qcur (2048)
    hipMemsetAsync(bcur, 0, 4096, stream);
    binpass_kernel<<<2 * NPBB, 256, 0, stream>>>(ru_src, ru_dst, ur_src, ur_dst,
                                                 bcur, pairs);
    bbase_kernel<<<2, 128, 0, stream>>>(bcur, bbase, rs_u, rs_r);
    fillpass_kernel<<<2 * NBS, 256, 0, stream>>>(pairs, bcur, bbase,
                                                 rs_u, rs_r, csr_u, csr_r);

    // ---- 3 SAGE layers: 2 fused launches per layer ----
    const float* cu = x_user;
    const float* cr = x_rest;
    float* nu_[3] = {hu0, hu1, hu0};
    float* nr_[3] = {hr0, hr1, hr0};
    const int ggrid = (NR + NU + 3) / 4;   // 62500

    for (int l = 0; l < 3; l++) {
        const float* Wl2 = Wl + (size_t)l * 2 * DD * DD;
        const float* Wr2 = Wr + (size_t)l * 2 * DD * DD;
        const float* bl2 = bl + (size_t)l * 2 * DD;
        int relu = (l < 2) ? 1 : 0;
        gather2_kernel<<<ggrid, 256, 0, stream>>>(cu, csr_r, rs_r, mean_r,
                                                  cr, csr_u, rs_u, mean_u);
        sage_fused_kernel<<<NBR + NBU, 256, 0, stream>>>(mean_r, cr, mean_u, cu,
                                                         Wl2, Wr2, bl2,
                                                         nr_[l], nu_[l], relu);
        cu = nu_[l];
        cr = nr_[l];
    }
    // ---- decoder: precompute P, bin queries by Pu window, GEMM decode -----
    float* P_u = hu1;
    float* P_r = hr1;
    pre_fused_kernel<<<NBU + NBR, 256, 0, stream>>>(cu, cr, dW1, db1, P_u, P_r);
    qbin_kernel<<<NQB, 256, 0, stream>>>(el_row, el_col, qcur, qpairs);
    qdec3_kernel<<<2 * NQW, 256, 0, stream>>>(P_u, P_r, qpairs, qcur,
                                              dW2, db2, dW3, db3, out);
}